// Round 9
// baseline (94.517 us; speedup 1.0000x reference)
//
#include <hip/hip_runtime.h>

typedef unsigned short u16;
typedef unsigned int u32;
typedef _Float16 f16;
typedef __attribute__((ext_vector_type(8))) _Float16 f16x8;
typedef __attribute__((ext_vector_type(4))) float f32x4;

constexpr int SEQ = 2048;
constexpr int EMBD = 1024;
constexpr int HD = 128;
constexpr int NB = 8;
constexpr int NSLS = 8;  // slices in stats pass
constexpr int NSLP = 4;  // slices in PV pass

__device__ inline u16 f2h(float f) { return __builtin_bit_cast(u16, (f16)f); }
__device__ inline u32 pack2(float a, float b) { return (u32)f2h(a) | ((u32)f2h(b) << 16); }

__device__ inline f32x4 mfma16(f16x8 a, f16x8 b, f32x4 c) {
  return __builtin_amdgcn_mfma_f32_16x16x32_f16(a, b, c, 0, 0, 0);
}

__device__ __forceinline__ void gload16(const u16* g, u16* l) {
  __builtin_amdgcn_global_load_lds(
      (const __attribute__((address_space(1))) u32*)g,
      (__attribute__((address_space(3))) u32*)l, 16, 0, 0);
}

// Swizzled fragment read: tiles stored (LDS and global scratch) row-major with
// within-row chunk XOR: byte ^= (row&7)<<4 (element ^= (row&7)<<3).
template<int RB>
__device__ inline f16x8 frag_ld(const u16* lds, int row, int e) {
  int byte = row * RB + ((e * 2) ^ ((row & 7) << 4));
  return *reinterpret_cast<const f16x8*>(reinterpret_cast<const char*>(lds) + byte);
}

// --------- weights: Wt[k0t][H][e] pre-swizzled tiles, H = w*128+h ------------
__global__ __launch_bounds__(256) void k_cvt_w(const float* __restrict__ Wq,
                                               const float* __restrict__ Wk,
                                               const float* __restrict__ Wv,
                                               u16* __restrict__ Wt) {
  int t = blockIdx.x * 256 + threadIdx.x;  // 98304
  int e0 = (t & 255) * 4;
  int H = t >> 8;  // 0..383
  int w = H >> 7, h = H & 127;
  const float* W = (w == 0) ? Wq : (w == 1) ? Wk : Wv;
  ushort4 o;
  o.x = f2h(W[(size_t)(e0 + 0) * HD + h]);
  o.y = f2h(W[(size_t)(e0 + 1) * HD + h]);
  o.z = f2h(W[(size_t)(e0 + 2) * HD + h]);
  o.w = f2h(W[(size_t)(e0 + 3) * HD + h]);
  int k0t = e0 >> 6, ec = e0 & 63;
  size_t el = (size_t)(k0t * 384 + H) * 64 + (ec ^ ((H & 7) << 3));
  *reinterpret_cast<ushort4*>(Wt + el) = o;
}

// --------- fused projections, 2-deep x register prefetch (r5 version) --------
__global__ __launch_bounds__(512, 4) void k_proj(const float* __restrict__ x,
                                                 const u16* __restrict__ Wt,
                                                 u16* __restrict__ Qb,
                                                 u16* __restrict__ Kb,
                                                 u16* __restrict__ Vtb) {
  __shared__ __align__(16) u16 As[2][64 * 64];    // 16KB
  __shared__ __align__(16) u16 Bs[2][192 * 64];   // 48KB
  const int mt = blockIdx.x, ny = blockIdx.y;
  const int t = threadIdx.x, lane = t & 63, wave = t >> 6;
  const int rh = (wave & 1) * 32, cq = (wave >> 1) * 48;
  const int ar = t >> 3, ac = t & 7;
  const float* asrc = x + (size_t)(mt * 64 + ar) * EMBD + ac * 8;
  const int adst = ar * 64 + ((ac * 8) ^ ((ar & 7) << 3));
  f32x4 zero = {0.f, 0.f, 0.f, 0.f};
  f32x4 acc[2][3];
#pragma unroll
  for (int a = 0; a < 2; ++a)
#pragma unroll
    for (int b = 0; b < 3; ++b) acc[a][b] = zero;

  float4 xe0, xe1, xo0, xo1;
  xe0 = *reinterpret_cast<const float4*>(asrc);
  xe1 = *reinterpret_cast<const float4*>(asrc + 4);
#pragma unroll
  for (int q = 0; q < 3; ++q) {
    int lin = q * 512 + t;
    gload16(Wt + ny * 12288 + lin * 8, &Bs[0][lin * 8]);
  }
  {
    uint4 o = {pack2(xe0.x, xe0.y), pack2(xe0.z, xe0.w), pack2(xe1.x, xe1.y), pack2(xe1.z, xe1.w)};
    *reinterpret_cast<uint4*>(&As[0][adst]) = o;
  }
  xo0 = *reinterpret_cast<const float4*>(asrc + 64);
  xo1 = *reinterpret_cast<const float4*>(asrc + 68);
  __syncthreads();
#pragma unroll 2
  for (int s = 0; s < 16; ++s) {
    const int cur = s & 1;
    if (s + 1 < 16) {
#pragma unroll
      for (int q = 0; q < 3; ++q) {
        int lin = q * 512 + t;
        gload16(Wt + (s + 1) * 24576 + ny * 12288 + lin * 8, &Bs[cur ^ 1][lin * 8]);
      }
    }
    if (s + 2 < 16) {
      if (cur == 0) {
        xe0 = *reinterpret_cast<const float4*>(asrc + (s + 2) * 64);
        xe1 = *reinterpret_cast<const float4*>(asrc + (s + 2) * 64 + 4);
      } else {
        xo0 = *reinterpret_cast<const float4*>(asrc + (s + 2) * 64);
        xo1 = *reinterpret_cast<const float4*>(asrc + (s + 2) * 64 + 4);
      }
    }
    __builtin_amdgcn_s_setprio(1);
#pragma unroll
    for (int kk = 0; kk < 2; ++kk) {
      f16x8 af0 = frag_ld<128>(As[cur], rh + (lane & 15), kk * 32 + (lane >> 4) * 8);
      f16x8 af1 = frag_ld<128>(As[cur], rh + 16 + (lane & 15), kk * 32 + (lane >> 4) * 8);
#pragma unroll
      for (int fc = 0; fc < 3; ++fc) {
        f16x8 bw = frag_ld<128>(Bs[cur], cq + fc * 16 + (lane & 15), kk * 32 + (lane >> 4) * 8);
        acc[0][fc] = mfma16(af0, bw, acc[0][fc]);
        acc[1][fc] = mfma16(af1, bw, acc[1][fc]);
      }
    }
    __builtin_amdgcn_s_setprio(0);
    if (s + 1 < 16) {
      uint4 o;
      if (cur == 0)
        o = {pack2(xo0.x, xo0.y), pack2(xo0.z, xo0.w), pack2(xo1.x, xo1.y), pack2(xo1.z, xo1.w)};
      else
        o = {pack2(xe0.x, xe0.y), pack2(xe0.z, xe0.w), pack2(xe1.x, xe1.y), pack2(xe1.z, xe1.w)};
      *reinterpret_cast<uint4*>(&As[cur ^ 1][adst]) = o;
    }
    __syncthreads();
  }
#pragma unroll
  for (int fi = 0; fi < 2; ++fi)
#pragma unroll
    for (int fc = 0; fc < 3; ++fc) {
      int gcol = ny * 192 + cq + fc * 16 + (lane & 15);
      int w = gcol >> 7, h = gcol & 127;
      int i0 = mt * 64 + rh + fi * 16 + (lane >> 4) * 4;
      if (w < 2) {
        u16* P = w ? Kb : Qb;
#pragma unroll
        for (int r = 0; r < 4; ++r) {
          int i = i0 + r;
          P[(size_t)i * 128 + (h ^ ((i & 7) << 3))] = f2h(acc[fi][fc][r]);
        }
      } else {
        int bb = i0 >> 11, jt = (i0 >> 6) & 31, tl = i0 & 63;
        ushort4 o = {f2h(acc[fi][fc][0]), f2h(acc[fi][fc][1]),
                     f2h(acc[fi][fc][2]), f2h(acc[fi][fc][3])};
        size_t el = ((size_t)(bb * 32 + jt) * 128 + h) * 64 + (tl ^ ((h & 7) << 3));
        *reinterpret_cast<ushort4*>(Vtb + el) = o;
      }
    }
}

__device__ inline void merge_ml(float& m, float& l, float m2, float l2) {
  float mn = fmaxf(m, m2);
  float a = (m > -1e37f) ? l * __expf(m - mn) : 0.f;
  float b = (m2 > -1e37f) ? l2 * __expf(m2 - mn) : 0.f;
  m = mn;
  l = a + b;
}

// --------- stats pass v2: wave owns 64 j-rows (af[4][4]); K fully in regs ----
// 512 blocks = 8 bb x 8 zp x 8 sl; 256-row j-blocks paired (zp, 7-zp).
__global__ __launch_bounds__(256, 2) void k_statsA(const u16* __restrict__ Qb,
                                                   const u16* __restrict__ Kb,
                                                   float* __restrict__ mpart,
                                                   float* __restrict__ lpart) {
  __shared__ __align__(16) u16 Qs[2][128 * 128];  // 2x32KB
  const int id = blockIdx.x;
  const int bb = id & 7, zp = (id >> 3) & 7, sl = id >> 6;
  const int t = threadIdx.x, lane = t & 63, wave = t >> 6;
  f32x4 zero = {0.f, 0.f, 0.f, 0.f};

  for (int ph = 0; ph < 2; ++ph) {
    const int jb = ph ? 7 - zp : zp;  // 256-row j-block
    __syncthreads();  // prev-phase readers done before restaging
    // stage K rows [256jb, 256jb+256) across both buffers (64KB)
#pragma unroll
    for (int q = 0; q < 16; ++q) {
      int lin = q * 256 + t;  // 0..4095 chunks of 8 elems
      gload16(Kb + ((size_t)bb * SEQ + jb * 256) * 128 + lin * 8, &Qs[0][lin * 8]);
    }
    __syncthreads();
    // wave owns block-local j-rows [64*wave, 64*wave+64): af[4][4] = 64 VGPRs
    f16x8 af[4][4];
#pragma unroll
    for (int fj = 0; fj < 4; ++fj)
#pragma unroll
      for (int kk = 0; kk < 4; ++kk) {
        int row = wave * 64 + fj * 16 + (lane & 15);
        af[fj][kk] = frag_ld<256>(Qs[row >> 7], row & 127, kk * 32 + (lane >> 4) * 8);
      }
    float m[4][4], l[4][4];
#pragma unroll
    for (int fj = 0; fj < 4; ++fj)
#pragma unroll
      for (int r = 0; r < 4; ++r) {
        m[fj][r] = -INFINITY;
        l[fj][r] = 0.f;
      }
    __syncthreads();  // all af reads done before Q overwrites K image
    const int itb = 2 * jb;
    const int it0 = itb + ((sl - itb) & 7);
    int cur = 0;
    if (it0 < 16) {
#pragma unroll
      for (int q = 0; q < 8; ++q) {
        int lin = q * 256 + t;
        gload16(Qb + ((size_t)bb * SEQ + it0 * 128) * 128 + lin * 8, &Qs[0][lin * 8]);
      }
      for (int it = it0; it < 16; it += 8) {
        __syncthreads();  // stage(cur) landed; readers of cur^1 drained
        if (it + 8 < 16) {
#pragma unroll
          for (int q = 0; q < 8; ++q) {
            int lin = q * 256 + t;
            gload16(Qb + ((size_t)bb * SEQ + (it + 8) * 128) * 128 + lin * 8,
                    &Qs[cur ^ 1][lin * 8]);
          }
        }
        const bool diag = (it <= 2 * jb + 1);
#pragma unroll
        for (int h = 0; h < 2; ++h) {  // two fi-halves keep acc at 64 VGPRs
          f32x4 acc[4][4];
#pragma unroll
          for (int a = 0; a < 4; ++a)
#pragma unroll
            for (int b = 0; b < 4; ++b) acc[a][b] = zero;
          __builtin_amdgcn_s_setprio(1);
#pragma unroll
          for (int kk = 0; kk < 4; ++kk)
#pragma unroll
            for (int fi = 0; fi < 4; ++fi) {
              f16x8 bq = frag_ld<256>(Qs[cur], (h * 4 + fi) * 16 + (lane & 15),
                                      kk * 32 + (lane >> 4) * 8);
#pragma unroll
              for (int fj = 0; fj < 4; ++fj)
                acc[fj][fi] = mfma16(af[fj][kk], bq, acc[fj][fi]);
            }
          __builtin_amdgcn_s_setprio(0);
          if (diag) {  // masked path
#pragma unroll
            for (int fj = 0; fj < 4; ++fj)
#pragma unroll
              for (int r = 0; r < 4; ++r) {
                int jg = jb * 256 + wave * 64 + fj * 16 + (lane >> 4) * 4 + r;
                float v[4];
                float vmax = -INFINITY;
#pragma unroll
                for (int fi = 0; fi < 4; ++fi) {
                  int ig = it * 128 + (h * 4 + fi) * 16 + (lane & 15);
                  v[fi] = (ig >= jg) ? acc[fj][fi][r] : -INFINITY;
                  vmax = fmaxf(vmax, v[fi]);
                }
                if (vmax > -1e37f) {
                  float mn = fmaxf(m[fj][r], vmax);
                  float sc = (m[fj][r] > -1e37f) ? __expf(m[fj][r] - mn) : 0.f;
                  float ss = 0.f;
#pragma unroll
                  for (int fi = 0; fi < 4; ++fi)
                    ss += (v[fi] > -1e37f) ? __expf(v[fi] - mn) : 0.f;
                  l[fj][r] = l[fj][r] * sc + ss;
                  m[fj][r] = mn;
                }
              }
          } else {  // off-diagonal: branchless
#pragma unroll
            for (int fj = 0; fj < 4; ++fj)
#pragma unroll
              for (int r = 0; r < 4; ++r) {
                float vmax = acc[fj][0][r];
#pragma unroll
                for (int fi = 1; fi < 4; ++fi) vmax = fmaxf(vmax, acc[fj][fi][r]);
                float mn = fmaxf(m[fj][r], vmax);
                float sc = __expf(m[fj][r] - mn);
                float ss = 0.f;
#pragma unroll
                for (int fi = 0; fi < 4; ++fi) ss += __expf(acc[fj][fi][r] - mn);
                l[fj][r] = l[fj][r] * sc + ss;
                m[fj][r] = mn;
              }
          }
        }
        cur ^= 1;
      }
    }
    // merge across the 16 i-lanes
#pragma unroll
    for (int fj = 0; fj < 4; ++fj)
#pragma unroll
      for (int r = 0; r < 4; ++r)
        for (int msk = 1; msk <= 8; msk <<= 1) {
          float m2 = __shfl_xor(m[fj][r], msk);
          float l2 = __shfl_xor(l[fj][r], msk);
          merge_ml(m[fj][r], l[fj][r], m2, l2);
        }
    if ((lane & 15) == 0) {
#pragma unroll
      for (int fj = 0; fj < 4; ++fj)
#pragma unroll
        for (int r = 0; r < 4; ++r) {
          int j = jb * 256 + wave * 64 + fj * 16 + (lane >> 4) * 4 + r;
          size_t idx = (size_t)sl * (NB * SEQ) + (size_t)bb * SEQ + j;
          mpart[idx] = m[fj][r];
          lpart[idx] = l[fj][r];
        }
    }
  }
}

// C_j = m_j + ln(l_j)
__global__ __launch_bounds__(256) void k_stats_reduce(const float* __restrict__ mpart,
                                                      const float* __restrict__ lpart,
                                                      float* __restrict__ Cg) {
  int idx = blockIdx.x * 256 + threadIdx.x;
  float m = -INFINITY;
#pragma unroll
  for (int sl = 0; sl < NSLS; sl++) m = fmaxf(m, mpart[sl * (NB * SEQ) + idx]);
  float l = 0.f;
#pragma unroll
  for (int sl = 0; sl < NSLS; sl++) {
    float ms = mpart[sl * (NB * SEQ) + idx];
    if (ms > -1e37f) l += lpart[sl * (NB * SEQ) + idx] * __expf(ms - m);
  }
  Cg[idx] = m + __logf(l);
}

// --------- PV pass (r5 version): 64-row i-tiles, NSLP=4, 512 blocks ----------
__global__ __launch_bounds__(256, 2) void k_passB(const u16* __restrict__ Qb,
                                                  const u16* __restrict__ Kb,
                                                  const u16* __restrict__ Vtb,
                                                  const float* __restrict__ Cg,
                                                  u16* __restrict__ opart) {
  __shared__ __align__(16) u16 Ks2[2][64 * 128];  // 2x16KB
  __shared__ __align__(16) u16 Vs2[2][128 * 64];  // 2x16KB
  __shared__ __align__(16) u16 Ps[64 * 64];       // 8KB (72KB total, 2 blk/CU)
  const int id = blockIdx.x;
  const int bb = id & 7, zp = (id >> 3) & 15, sl = id >> 7;
  const int t = threadIdx.x, lane = t & 63, wave = t >> 6;
  f32x4 zero = {0.f, 0.f, 0.f, 0.f};

  auto stageKV = [&](int jt, int b) {
#pragma unroll
    for (int q = 0; q < 4; ++q) {
      int lin = q * 256 + t;
      gload16(Kb + ((size_t)bb * SEQ + jt * 64) * 128 + lin * 8, &Ks2[b][lin * 8]);
    }
#pragma unroll
    for (int q = 0; q < 4; ++q) {
      int lin = q * 256 + t;
      gload16(Vtb + ((size_t)bb * 32 + jt) * 8192 + lin * 8, &Vs2[b][lin * 8]);
    }
  };

  for (int ph = 0; ph < 2; ++ph) {
    const int it = ph ? 31 - zp : zp;  // 64-row i-tile index
    f16x8 qf[4];
#pragma unroll
    for (int kk = 0; kk < 4; ++kk) {
      size_t gi = (size_t)bb * SEQ + it * 64 + wave * 16 + (lane & 15);
      int e0 = kk * 32 + (lane >> 4) * 8;
      qf[kk] = *reinterpret_cast<const f16x8*>(Qb + gi * 128 + (e0 ^ (((int)gi & 7) << 3)));
    }
    f32x4 accO[8];
#pragma unroll
    for (int b = 0; b < 8; ++b) accO[b] = zero;
    __syncthreads();  // prev-phase LDS readers done
    if (sl <= it) stageKV(sl, 0);
    int cur = 0;
    for (int jt = sl; jt <= it; jt += NSLP) {
      __syncthreads();  // stage(jt) landed; prev readers of cur done
      if (jt + NSLP <= it) stageKV(jt + NSLP, cur ^ 1);  // hides under QK+exp+PV
      float cj[4];
#pragma unroll
      for (int fj = 0; fj < 4; ++fj)
        cj[fj] = Cg[bb * SEQ + jt * 64 + fj * 16 + (lane & 15)];
      f32x4 accS[4];
#pragma unroll
      for (int b = 0; b < 4; ++b) accS[b] = zero;
      __builtin_amdgcn_s_setprio(1);
#pragma unroll
      for (int kk = 0; kk < 4; ++kk)
#pragma unroll
        for (int fj = 0; fj < 4; ++fj) {
          f16x8 bk = frag_ld<256>(Ks2[cur], fj * 16 + (lane & 15), kk * 32 + (lane >> 4) * 8);
          accS[fj] = mfma16(qf[kk], bk, accS[fj]);
        }
      __builtin_amdgcn_s_setprio(0);
#pragma unroll
      for (int fj = 0; fj < 4; ++fj) {
        int jloc = fj * 16 + (lane & 15);
        int jg = jt * 64 + jloc;
        float c = cj[fj];
#pragma unroll
        for (int r = 0; r < 4; ++r) {
          int iloc = wave * 16 + (lane >> 4) * 4 + r;
          int ig = it * 64 + iloc;
          float p = __expf(accS[fj][r] - c);
          if (ig < jg) p = 0.f;
          Ps[iloc * 64 + (jloc ^ ((iloc & 7) << 3))] = f2h(p);
        }
      }
      // PV: wave-private P rows -> lgkm ordering only, no barrier
      __builtin_amdgcn_s_setprio(1);
#pragma unroll
      for (int ks = 0; ks < 2; ++ks) {
        f16x8 pa = frag_ld<128>(Ps, wave * 16 + (lane & 15), ks * 32 + (lane >> 4) * 8);
#pragma unroll
        for (int fh = 0; fh < 8; ++fh) {
          f16x8 bv = frag_ld<128>(Vs2[cur], fh * 16 + (lane & 15), ks * 32 + (lane >> 4) * 8);
          accO[fh] = mfma16(pa, bv, accO[fh]);
        }
      }
      __builtin_amdgcn_s_setprio(0);
      cur ^= 1;
    }
#pragma unroll
    for (int fh = 0; fh < 8; ++fh)
#pragma unroll
      for (int r = 0; r < 4; ++r) {
        int ig = it * 64 + wave * 16 + (lane >> 4) * 4 + r;
        int h = fh * 16 + (lane & 15);
        opart[(((size_t)sl * NB + bb) * SEQ + ig) * HD + h] = f2h(accO[fh][r]);
      }
  }
}

__global__ __launch_bounds__(256) void k_reduceB(const u16* __restrict__ opart,
                                                 float* __restrict__ out) {
  size_t base = ((size_t)blockIdx.x * 256 + threadIdx.x) * 8;
  const size_t S = (size_t)NB * SEQ * HD;
  float s[8];
#pragma unroll
  for (int j = 0; j < 8; j++) s[j] = 0.f;
#pragma unroll
  for (int sl = 0; sl < NSLP; sl++) {
    f16x8 v = *reinterpret_cast<const f16x8*>(opart + sl * S + base);
#pragma unroll
    for (int j = 0; j < 8; j++) s[j] += (float)v[j];
  }
  float4 o0 = {s[0], s[1], s[2], s[3]};
  float4 o1 = {s[4], s[5], s[6], s[7]};
  *reinterpret_cast<float4*>(out + base) = o0;
  *reinterpret_cast<float4*>(out + base + 4) = o1;
}

extern "C" void kernel_launch(void* const* d_in, const int* in_sizes, int n_in,
                              void* d_out, int out_size, void* d_ws, size_t ws_size,
                              hipStream_t stream) {
  (void)in_sizes; (void)n_in; (void)out_size; (void)ws_size;
  const float* x = (const float*)d_in[0];
  const float* Wk = (const float*)d_in[1];
  const float* Wq = (const float*)d_in[2];
  const float* Wv = (const float*)d_in[3];
  float* out = (float*)d_out;
  char* ws = (char*)d_ws;

  u16* Wt = (u16*)(ws + 0);                //   786,432 B (pre-swizzled tiles)
  u16* Qb = (u16*)(ws + 786432);           // 4,194,304 B (pre-swizzled)
  u16* Kb = (u16*)(ws + 4980736);          // 4,194,304 B (pre-swizzled)
  u16* Vtb = (u16*)(ws + 9175040);         // 4,194,304 B (pre-swizzled tiles)
  float* mpart = (float*)(ws + 13369344);  //   524,288 B
  float* lpart = (float*)(ws + 13893632);  //   524,288 B
  float* Cg = (float*)(ws + 14417920);     //    65,536 B
  u16* opart = (u16*)(ws + 14548992);      // 16,777,216 B (total ~31.3 MB)

  k_cvt_w<<<384, 256, 0, stream>>>(Wq, Wk, Wv, Wt);
  k_proj<<<dim3(256, 2), 512, 0, stream>>>(x, Wt, Qb, Kb, Vtb);
  k_statsA<<<512, 256, 0, stream>>>(Qb, Kb, mpart, lpart);
  k_stats_reduce<<<64, 256, 0, stream>>>(mpart, lpart, Cg);
  k_passB<<<512, 256, 0, stream>>>(Qb, Kb, Vtb, Cg, opart);
  k_reduceB<<<1024, 256, 0, stream>>>(opart, out);
}

// Round 10
// 80.767 us; speedup vs baseline: 1.1702x; 1.1702x over previous
//
#include <hip/hip_runtime.h>

typedef unsigned short u16;
typedef unsigned int u32;
typedef _Float16 f16;
typedef __attribute__((ext_vector_type(8))) _Float16 f16x8;
typedef __attribute__((ext_vector_type(4))) float f32x4;
typedef __attribute__((ext_vector_type(16))) float f32x16;

constexpr int SEQ = 2048;
constexpr int EMBD = 1024;
constexpr int HD = 128;
constexpr int NB = 8;
constexpr int NSLS = 8;  // slices in stats pass
constexpr int NSLP = 8;  // slices in PV pass

__device__ inline u16 f2h(float f) { return __builtin_bit_cast(u16, (f16)f); }
__device__ inline u32 pack2(float a, float b) { return (u32)f2h(a) | ((u32)f2h(b) << 16); }

__device__ inline f32x4 mfma16(f16x8 a, f16x8 b, f32x4 c) {
  return __builtin_amdgcn_mfma_f32_16x16x32_f16(a, b, c, 0, 0, 0);
}
__device__ inline f32x16 mfma32(f16x8 a, f16x8 b, f32x16 c) {
  return __builtin_amdgcn_mfma_f32_32x32x16_f16(a, b, c, 0, 0, 0);
}

__device__ __forceinline__ void gload16(const u16* g, u16* l) {
  __builtin_amdgcn_global_load_lds(
      (const __attribute__((address_space(1))) u32*)g,
      (__attribute__((address_space(3))) u32*)l, 16, 0, 0);
}

// Swizzled fragment read: tiles stored (LDS and global scratch) row-major with
// within-row chunk XOR: byte ^= (row&7)<<4 (element ^= (row&7)<<3).
template<int RB>
__device__ inline f16x8 frag_ld(const u16* lds, int row, int e) {
  int byte = row * RB + ((e * 2) ^ ((row & 7) << 4));
  return *reinterpret_cast<const f16x8*>(reinterpret_cast<const char*>(lds) + byte);
}

// --------- weights: Wt[k0t][H][e] pre-swizzled tiles, H = w*128+h ------------
__global__ __launch_bounds__(256) void k_cvt_w(const float* __restrict__ Wq,
                                               const float* __restrict__ Wk,
                                               const float* __restrict__ Wv,
                                               u16* __restrict__ Wt) {
  int t = blockIdx.x * 256 + threadIdx.x;  // 98304
  int e0 = (t & 255) * 4;
  int H = t >> 8;  // 0..383
  int w = H >> 7, h = H & 127;
  const float* W = (w == 0) ? Wq : (w == 1) ? Wk : Wv;
  ushort4 o;
  o.x = f2h(W[(size_t)(e0 + 0) * HD + h]);
  o.y = f2h(W[(size_t)(e0 + 1) * HD + h]);
  o.z = f2h(W[(size_t)(e0 + 2) * HD + h]);
  o.w = f2h(W[(size_t)(e0 + 3) * HD + h]);
  int k0t = e0 >> 6, ec = e0 & 63;
  size_t el = (size_t)(k0t * 384 + H) * 64 + (ec ^ ((H & 7) << 3));
  *reinterpret_cast<ushort4*>(Wt + el) = o;
}

// --------- fused projections, 2-deep x register prefetch (r5 version) --------
__global__ __launch_bounds__(512, 4) void k_proj(const float* __restrict__ x,
                                                 const u16* __restrict__ Wt,
                                                 u16* __restrict__ Qb,
                                                 u16* __restrict__ Kb,
                                                 u16* __restrict__ Vtb) {
  __shared__ __align__(16) u16 As[2][64 * 64];    // 16KB
  __shared__ __align__(16) u16 Bs[2][192 * 64];   // 48KB
  const int mt = blockIdx.x, ny = blockIdx.y;
  const int t = threadIdx.x, lane = t & 63, wave = t >> 6;
  const int rh = (wave & 1) * 32, cq = (wave >> 1) * 48;
  const int ar = t >> 3, ac = t & 7;
  const float* asrc = x + (size_t)(mt * 64 + ar) * EMBD + ac * 8;
  const int adst = ar * 64 + ((ac * 8) ^ ((ar & 7) << 3));
  f32x4 zero = {0.f, 0.f, 0.f, 0.f};
  f32x4 acc[2][3];
#pragma unroll
  for (int a = 0; a < 2; ++a)
#pragma unroll
    for (int b = 0; b < 3; ++b) acc[a][b] = zero;

  float4 xe0, xe1, xo0, xo1;
  xe0 = *reinterpret_cast<const float4*>(asrc);
  xe1 = *reinterpret_cast<const float4*>(asrc + 4);
#pragma unroll
  for (int q = 0; q < 3; ++q) {
    int lin = q * 512 + t;
    gload16(Wt + ny * 12288 + lin * 8, &Bs[0][lin * 8]);
  }
  {
    uint4 o = {pack2(xe0.x, xe0.y), pack2(xe0.z, xe0.w), pack2(xe1.x, xe1.y), pack2(xe1.z, xe1.w)};
    *reinterpret_cast<uint4*>(&As[0][adst]) = o;
  }
  xo0 = *reinterpret_cast<const float4*>(asrc + 64);
  xo1 = *reinterpret_cast<const float4*>(asrc + 68);
  __syncthreads();
#pragma unroll 2
  for (int s = 0; s < 16; ++s) {
    const int cur = s & 1;
    if (s + 1 < 16) {
#pragma unroll
      for (int q = 0; q < 3; ++q) {
        int lin = q * 512 + t;
        gload16(Wt + (s + 1) * 24576 + ny * 12288 + lin * 8, &Bs[cur ^ 1][lin * 8]);
      }
    }
    if (s + 2 < 16) {
      if (cur == 0) {
        xe0 = *reinterpret_cast<const float4*>(asrc + (s + 2) * 64);
        xe1 = *reinterpret_cast<const float4*>(asrc + (s + 2) * 64 + 4);
      } else {
        xo0 = *reinterpret_cast<const float4*>(asrc + (s + 2) * 64);
        xo1 = *reinterpret_cast<const float4*>(asrc + (s + 2) * 64 + 4);
      }
    }
    __builtin_amdgcn_s_setprio(1);
#pragma unroll
    for (int kk = 0; kk < 2; ++kk) {
      f16x8 af0 = frag_ld<128>(As[cur], rh + (lane & 15), kk * 32 + (lane >> 4) * 8);
      f16x8 af1 = frag_ld<128>(As[cur], rh + 16 + (lane & 15), kk * 32 + (lane >> 4) * 8);
#pragma unroll
      for (int fc = 0; fc < 3; ++fc) {
        f16x8 bw = frag_ld<128>(Bs[cur], cq + fc * 16 + (lane & 15), kk * 32 + (lane >> 4) * 8);
        acc[0][fc] = mfma16(af0, bw, acc[0][fc]);
        acc[1][fc] = mfma16(af1, bw, acc[1][fc]);
      }
    }
    __builtin_amdgcn_s_setprio(0);
    if (s + 1 < 16) {
      uint4 o;
      if (cur == 0)
        o = {pack2(xo0.x, xo0.y), pack2(xo0.z, xo0.w), pack2(xo1.x, xo1.y), pack2(xo1.z, xo1.w)};
      else
        o = {pack2(xe0.x, xe0.y), pack2(xe0.z, xe0.w), pack2(xe1.x, xe1.y), pack2(xe1.z, xe1.w)};
      *reinterpret_cast<uint4*>(&As[cur ^ 1][adst]) = o;
    }
    __syncthreads();
  }
#pragma unroll
  for (int fi = 0; fi < 2; ++fi)
#pragma unroll
    for (int fc = 0; fc < 3; ++fc) {
      int gcol = ny * 192 + cq + fc * 16 + (lane & 15);
      int w = gcol >> 7, h = gcol & 127;
      int i0 = mt * 64 + rh + fi * 16 + (lane >> 4) * 4;
      if (w < 2) {
        u16* P = w ? Kb : Qb;
#pragma unroll
        for (int r = 0; r < 4; ++r) {
          int i = i0 + r;
          P[(size_t)i * 128 + (h ^ ((i & 7) << 3))] = f2h(acc[fi][fc][r]);
        }
      } else {
        int bb = i0 >> 11, jt = (i0 >> 6) & 31, tl = i0 & 63;
        ushort4 o = {f2h(acc[fi][fc][0]), f2h(acc[fi][fc][1]),
                     f2h(acc[fi][fc][2]), f2h(acc[fi][fc][3])};
        size_t el = ((size_t)(bb * 32 + jt) * 128 + h) * 64 + (tl ^ ((h & 7) << 3));
        *reinterpret_cast<ushort4*>(Vtb + el) = o;
      }
    }
}

__device__ inline void merge_ml(float& m, float& l, float m2, float l2) {
  float mn = fmaxf(m, m2);
  float a = (m > -1e37f) ? l * __expf(m - mn) : 0.f;
  float b = (m2 > -1e37f) ? l2 * __expf(m2 - mn) : 0.f;
  m = mn;
  l = a + b;
}

// --------- stats pass (r5 version): 256 thr, wave owns 32 j-cols -------------
__global__ __launch_bounds__(256, 2) void k_statsA(const u16* __restrict__ Qb,
                                                   const u16* __restrict__ Kb,
                                                   float* __restrict__ mpart,
                                                   float* __restrict__ lpart) {
  __shared__ __align__(16) u16 Qs[2][128 * 128];  // 2x32KB
  const int id = blockIdx.x;
  const int bb = id & 7, z = (id >> 3) & 7, sl = id >> 6;
  const int t = threadIdx.x, lane = t & 63, wj = (t >> 6) * 32;
  f32x4 zero = {0.f, 0.f, 0.f, 0.f};

  for (int ph = 0; ph < 2; ++ph) {
    const int jt = ph ? 15 - z : z;
    __syncthreads();
#pragma unroll
    for (int q = 0; q < 8; ++q) {
      int lin = q * 256 + t;
      gload16(Kb + ((size_t)bb * SEQ + jt * 128) * 128 + lin * 8, &Qs[0][lin * 8]);
    }
    __syncthreads();
    f16x8 af[2][4];
#pragma unroll
    for (int fj = 0; fj < 2; ++fj)
#pragma unroll
      for (int kk = 0; kk < 4; ++kk)
        af[fj][kk] = frag_ld<256>(Qs[0], wj + fj * 16 + (lane & 15), kk * 32 + (lane >> 4) * 8);
    float m[2][4], l[2][4];
#pragma unroll
    for (int a = 0; a < 2; ++a)
#pragma unroll
      for (int r = 0; r < 4; ++r) {
        m[a][r] = -INFINITY;
        l[a][r] = 0.f;
      }
    const int it0 = jt + ((sl - jt) & 7);
    int cur = 1;
    if (it0 < 16) {
#pragma unroll
      for (int q = 0; q < 8; ++q) {
        int lin = q * 256 + t;
        gload16(Qb + ((size_t)bb * SEQ + it0 * 128) * 128 + lin * 8, &Qs[1][lin * 8]);
      }
      for (int it = it0; it < 16; it += 8) {
        __syncthreads();
        if (it + 8 < 16) {
#pragma unroll
          for (int q = 0; q < 8; ++q) {
            int lin = q * 256 + t;
            gload16(Qb + ((size_t)bb * SEQ + (it + 8) * 128) * 128 + lin * 8,
                    &Qs[cur ^ 1][lin * 8]);
          }
        }
        f32x4 acc[2][8];
#pragma unroll
        for (int a = 0; a < 2; ++a)
#pragma unroll
          for (int b = 0; b < 8; ++b) acc[a][b] = zero;
        __builtin_amdgcn_s_setprio(1);
#pragma unroll
        for (int kk = 0; kk < 4; ++kk)
#pragma unroll
          for (int fi = 0; fi < 8; ++fi) {
            f16x8 bq = frag_ld<256>(Qs[cur], fi * 16 + (lane & 15), kk * 32 + (lane >> 4) * 8);
            acc[0][fi] = mfma16(af[0][kk], bq, acc[0][fi]);
            acc[1][fi] = mfma16(af[1][kk], bq, acc[1][fi]);
          }
        __builtin_amdgcn_s_setprio(0);
        if (it == jt) {  // diagonal: masked path
#pragma unroll
          for (int fj = 0; fj < 2; ++fj)
#pragma unroll
            for (int r = 0; r < 4; ++r) {
              int jg = jt * 128 + wj + fj * 16 + (lane >> 4) * 4 + r;
              float v[8];
              float vmax = -INFINITY;
#pragma unroll
              for (int fi = 0; fi < 8; ++fi) {
                int ig = it * 128 + fi * 16 + (lane & 15);
                v[fi] = (ig >= jg) ? acc[fj][fi][r] : -INFINITY;
                vmax = fmaxf(vmax, v[fi]);
              }
              if (vmax > -1e37f) {
                float mn = fmaxf(m[fj][r], vmax);
                float sc = (m[fj][r] > -1e37f) ? __expf(m[fj][r] - mn) : 0.f;
                float ss = 0.f;
#pragma unroll
                for (int fi = 0; fi < 8; ++fi)
                  ss += (v[fi] > -1e37f) ? __expf(v[fi] - mn) : 0.f;
                l[fj][r] = l[fj][r] * sc + ss;
                m[fj][r] = mn;
              }
            }
        } else {  // off-diagonal: branchless (exp(-inf)=0)
#pragma unroll
          for (int fj = 0; fj < 2; ++fj)
#pragma unroll
            for (int r = 0; r < 4; ++r) {
              float vmax = acc[fj][0][r];
#pragma unroll
              for (int fi = 1; fi < 8; ++fi) vmax = fmaxf(vmax, acc[fj][fi][r]);
              float mn = fmaxf(m[fj][r], vmax);
              float sc = __expf(m[fj][r] - mn);
              float ss = 0.f;
#pragma unroll
              for (int fi = 0; fi < 8; ++fi) ss += __expf(acc[fj][fi][r] - mn);
              l[fj][r] = l[fj][r] * sc + ss;
              m[fj][r] = mn;
            }
        }
        cur ^= 1;
      }
    }
#pragma unroll
    for (int fj = 0; fj < 2; ++fj)
#pragma unroll
      for (int r = 0; r < 4; ++r)
        for (int msk = 1; msk <= 8; msk <<= 1) {
          float m2 = __shfl_xor(m[fj][r], msk);
          float l2 = __shfl_xor(l[fj][r], msk);
          merge_ml(m[fj][r], l[fj][r], m2, l2);
        }
    if ((lane & 15) == 0) {
#pragma unroll
      for (int fj = 0; fj < 2; ++fj)
#pragma unroll
        for (int r = 0; r < 4; ++r) {
          int j = jt * 128 + wj + fj * 16 + (lane >> 4) * 4 + r;
          size_t idx = (size_t)sl * (NB * SEQ) + (size_t)bb * SEQ + j;
          mpart[idx] = m[fj][r];
          lpart[idx] = l[fj][r];
        }
    }
  }
}

// C_j = m_j + ln(l_j)
__global__ __launch_bounds__(256) void k_stats_reduce(const float* __restrict__ mpart,
                                                      const float* __restrict__ lpart,
                                                      float* __restrict__ Cg) {
  int idx = blockIdx.x * 256 + threadIdx.x;
  float m = -INFINITY;
#pragma unroll
  for (int sl = 0; sl < NSLS; sl++) m = fmaxf(m, mpart[sl * (NB * SEQ) + idx]);
  float l = 0.f;
#pragma unroll
  for (int sl = 0; sl < NSLS; sl++) {
    float ms = mpart[sl * (NB * SEQ) + idx];
    if (ms > -1e37f) l += lpart[sl * (NB * SEQ) + idx] * __expf(ms - m);
  }
  Cg[idx] = m + __logf(l);
}

// --------- PV pass v3: 32x32x16 MFMA, wave owns 32 i-rows, Q in regs ---------
// 128-row i-tiles paired (z,15-z), NSLP=8 -> 512 balanced blocks, 80KB LDS.
__global__ __launch_bounds__(256, 2) void k_passB(const u16* __restrict__ Qb,
                                                  const u16* __restrict__ Kb,
                                                  const u16* __restrict__ Vtb,
                                                  const float* __restrict__ Cg,
                                                  u16* __restrict__ opart) {
  __shared__ __align__(16) u16 Ks2[2][64 * 128];  // 2x16KB
  __shared__ __align__(16) u16 Vs2[2][128 * 64];  // 2x16KB
  __shared__ __align__(16) u16 Ps[128 * 64];      // 16KB (80KB total, 2 blk/CU)
  const int id = blockIdx.x;
  const int bb = id & 7, z = (id >> 3) & 7, sl = id >> 6;
  const int t = threadIdx.x, lane = t & 63, wave = t >> 6;
  const int l31 = lane & 31, lh = lane >> 5;

  auto stageKV = [&](int jt, int b) {
#pragma unroll
    for (int q = 0; q < 4; ++q) {
      int lin = q * 256 + t;
      gload16(Kb + ((size_t)bb * SEQ + jt * 64) * 128 + lin * 8, &Ks2[b][lin * 8]);
    }
#pragma unroll
    for (int q = 0; q < 4; ++q) {
      int lin = q * 256 + t;
      gload16(Vtb + ((size_t)bb * 32 + jt) * 8192 + lin * 8, &Vs2[b][lin * 8]);
    }
  };

  for (int ph = 0; ph < 2; ++ph) {
    const int it = ph ? 15 - z : z;  // 128-row i-tile
    // Q fragments for this wave's 32 i-rows: qa[8 ksteps] = 32 VGPRs
    f16x8 qa[8];
    {
      size_t gi = (size_t)bb * SEQ + it * 128 + wave * 32 + l31;
      const u16* qrow = Qb + gi * 128;
      int sw = ((int)gi & 7) << 3;
#pragma unroll
      for (int ks = 0; ks < 8; ++ks) {
        int e0 = ks * 16 + lh * 8;
        qa[ks] = *reinterpret_cast<const f16x8*>(qrow + (e0 ^ sw));
      }
    }
    f32x16 accO[4];
#pragma unroll
    for (int b = 0; b < 4; ++b)
#pragma unroll
      for (int q = 0; q < 16; ++q) accO[b][q] = 0.f;
    const int jtmax = 2 * it + 1;
    __syncthreads();  // prev-phase LDS readers done
    if (sl <= jtmax) stageKV(sl, 0);
    int cur = 0;
    for (int jt = sl; jt <= jtmax; jt += NSLP) {
      __syncthreads();  // stage(jt) landed; prev readers of cur done
      if (jt + NSLP <= jtmax) stageKV(jt + NSLP, cur ^ 1);  // hides under QK+exp+PV
      float cj[2];
#pragma unroll
      for (int jtile = 0; jtile < 2; ++jtile)
        cj[jtile] = Cg[bb * SEQ + jt * 64 + jtile * 32 + l31];
      f32x16 accS[2];
#pragma unroll
      for (int b = 0; b < 2; ++b)
#pragma unroll
        for (int q = 0; q < 16; ++q) accS[b][q] = 0.f;
      __builtin_amdgcn_s_setprio(1);
#pragma unroll
      for (int ks = 0; ks < 8; ++ks)
#pragma unroll
        for (int jtile = 0; jtile < 2; ++jtile) {
          f16x8 bk = frag_ld<256>(Ks2[cur], jtile * 32 + l31, ks * 16 + lh * 8);
          accS[jtile] = mfma32(qa[ks], bk, accS[jtile]);
        }
      __builtin_amdgcn_s_setprio(0);
      // P = exp(S - C_j), causal-masked; wave-private 32 rows of Ps
#pragma unroll
      for (int jtile = 0; jtile < 2; ++jtile) {
        int jloc = jtile * 32 + l31;
        int jg = jt * 64 + jloc;
        float c = cj[jtile];
#pragma unroll
        for (int q = 0; q < 16; ++q) {
          int iloc = wave * 32 + (q & 3) + 8 * (q >> 2) + 4 * lh;
          int ig = it * 128 + iloc;
          float p = __expf(accS[jtile][q] - c);
          if (ig < jg) p = 0.f;
          Ps[iloc * 64 + (jloc ^ ((iloc & 7) << 3))] = f2h(p);
        }
      }
      // PV: A = wave-private P rows, B = V (all 128 h); no barrier needed
      __builtin_amdgcn_s_setprio(1);
#pragma unroll
      for (int js = 0; js < 4; ++js) {
        f16x8 pa = frag_ld<128>(Ps, wave * 32 + l31, js * 16 + lh * 8);
#pragma unroll
        for (int sh = 0; sh < 4; ++sh) {
          f16x8 bv = frag_ld<128>(Vs2[cur], sh * 32 + l31, js * 16 + lh * 8);
          accO[sh] = mfma32(pa, bv, accO[sh]);
        }
      }
      __builtin_amdgcn_s_setprio(0);
      cur ^= 1;
    }
#pragma unroll
    for (int sh = 0; sh < 4; ++sh) {
      int h = sh * 32 + l31;
#pragma unroll
      for (int q = 0; q < 16; ++q) {
        int ig = it * 128 + wave * 32 + (q & 3) + 8 * (q >> 2) + 4 * lh;
        opart[(((size_t)sl * NB + bb) * SEQ + ig) * HD + h] = f2h(accO[sh][q]);
      }
    }
  }
}

__global__ __launch_bounds__(256) void k_reduceB(const u16* __restrict__ opart,
                                                 float* __restrict__ out) {
  size_t base = ((size_t)blockIdx.x * 256 + threadIdx.x) * 8;
  const size_t S = (size_t)NB * SEQ * HD;
  float s[8];
#pragma unroll
  for (int j = 0; j < 8; j++) s[j] = 0.f;
#pragma unroll
  for (int sl = 0; sl < NSLP; sl++) {
    f16x8 v = *reinterpret_cast<const f16x8*>(opart + sl * S + base);
#pragma unroll
    for (int j = 0; j < 8; j++) s[j] += (float)v[j];
  }
  float4 o0 = {s[0], s[1], s[2], s[3]};
  float4 o1 = {s[4], s[5], s[6], s[7]};
  *reinterpret_cast<float4*>(out + base) = o0;
  *reinterpret_cast<float4*>(out + base + 4) = o1;
}

extern "C" void kernel_launch(void* const* d_in, const int* in_sizes, int n_in,
                              void* d_out, int out_size, void* d_ws, size_t ws_size,
                              hipStream_t stream) {
  (void)in_sizes; (void)n_in; (void)out_size; (void)ws_size;
  const float* x = (const float*)d_in[0];
  const float* Wk = (const float*)d_in[1];
  const float* Wq = (const float*)d_in[2];
  const float* Wv = (const float*)d_in[3];
  float* out = (float*)d_out;
  char* ws = (char*)d_ws;

  u16* Wt = (u16*)(ws + 0);                //   786,432 B (pre-swizzled tiles)
  u16* Qb = (u16*)(ws + 786432);           // 4,194,304 B (pre-swizzled)
  u16* Kb = (u16*)(ws + 4980736);          // 4,194,304 B (pre-swizzled)
  u16* Vtb = (u16*)(ws + 9175040);         // 4,194,304 B (pre-swizzled tiles)
  float* mpart = (float*)(ws + 13369344);  //   524,288 B
  float* lpart = (float*)(ws + 13893632);  //   524,288 B
  float* Cg = (float*)(ws + 14417920);     //    65,536 B
  u16* opart = (u16*)(ws + 14548992);      // 33,554,432 B (total ~48.1 MB)

  k_cvt_w<<<384, 256, 0, stream>>>(Wq, Wk, Wv, Wt);
  k_proj<<<dim3(256, 2), 512, 0, stream>>>(x, Wt, Qb, Kb, Vtb);
  k_statsA<<<512, 256, 0, stream>>>(Qb, Kb, mpart, lpart);
  k_stats_reduce<<<64, 256, 0, stream>>>(mpart, lpart, Cg);
  k_passB<<<512, 256, 0, stream>>>(Qb, Kb, Vtb, Cg, opart);
  k_reduceB<<<1024, 256, 0, stream>>>(opart, out);
}